// Round 1
// baseline (71.799 us; speedup 1.0000x reference)
//
#include <hip/hip_runtime.h>
#include <stdint.h>

#define B_ 32
#define N_ 1024
#define D_ 512
#define G_ 32
#define O_ 256

typedef __attribute__((ext_vector_type(8))) short short8;
typedef __attribute__((ext_vector_type(4))) float f32x4;

// round-to-nearest-even fp32 -> bf16 pair packed into u32 (low = a, high = b)
__device__ inline uint32_t pack_bf16x2(float a, float b) {
  uint32_t ua = __float_as_uint(a);
  uint32_t ub = __float_as_uint(b);
  ua += 0x7FFFu + ((ua >> 16) & 1u);
  ub += 0x7FFFu + ((ub >> 16) & 1u);
  return (ua >> 16) | (ub & 0xFFFF0000u);
}

// Pass 1: per block = (b, 128-row chunk). Computes pi via bf16 MFMA, then
// vector-FMA moments with register accumulators; writes per-block partials.
__global__ __launch_bounds__(512) void mdn_pass1(
    const float* __restrict__ x, const float* __restrict__ W,
    const float* __restrict__ bpi, float* __restrict__ ws)
{
  __shared__ uint32_t Xb[64 * 64];   // 64 rows x 128 bf16 (swizzled), 16KB
  __shared__ uint32_t Wb[32 * 64];   // 32 g x 128 bf16 (swizzled), 8KB
  __shared__ float SP[64 * 36];      // logits then pi, row stride 36 (16B-aligned)
  __shared__ float denom_acc[G_];
  __shared__ float bias_s[G_];

  const int t = threadIdx.x;
  const int bid = blockIdx.x;
  const int b = bid >> 3;
  const int n0 = (bid & 7) * 128;
  const int wave = t >> 6;
  const int lane = t & 63;
  const int Mt = wave >> 1;    // 0..3 : 16-row tile
  const int Nt = wave & 1;     // 0..1 : 16-g tile

  if (t < G_) { denom_acc[t] = 0.f; bias_s[t] = bpi[t]; }

  float4 macc[8];              // 32 accs: g = k*4+comp ; m1 if part==0 else m2
  #pragma unroll
  for (int k = 0; k < 8; ++k) macc[k] = make_float4(0.f, 0.f, 0.f, 0.f);

  for (int sc = 0; sc < 2; ++sc) {
    const int r0 = n0 + sc * 64;
    f32x4 acc = {0.f, 0.f, 0.f, 0.f};

    for (int dc = 0; dc < 4; ++dc) {
      __syncthreads();
      // ---- stage W d-chunk: 512 slots x 16B, linear LDS write, decoded src
      {
        int st = t * 16;
        int g = st >> 8;
        int d2 = (st & 255) ^ ((g & 7) << 4);
        int d = d2 >> 1;                       // multiple of 8
        const float4* src = (const float4*)(W + g * D_ + dc * 128 + d);
        float4 f0 = src[0], f1 = src[1];
        uint4 v;
        v.x = pack_bf16x2(f0.x, f0.y); v.y = pack_bf16x2(f0.z, f0.w);
        v.z = pack_bf16x2(f1.x, f1.y); v.w = pack_bf16x2(f1.z, f1.w);
        *(uint4*)((char*)Wb + st) = v;
      }
      // ---- stage X d-chunk: 1024 slots
      #pragma unroll
      for (int p = 0; p < 2; ++p) {
        int st = (p * 512 + t) * 16;
        int r = st >> 8;
        int d2 = (st & 255) ^ ((r & 7) << 4);
        int d = d2 >> 1;
        const float4* src =
            (const float4*)(x + ((size_t)b * N_ + r0 + r) * D_ + dc * 128 + d);
        float4 f0 = src[0], f1 = src[1];
        uint4 v;
        v.x = pack_bf16x2(f0.x, f0.y); v.y = pack_bf16x2(f0.z, f0.w);
        v.z = pack_bf16x2(f1.x, f1.y); v.w = pack_bf16x2(f1.z, f1.w);
        *(uint4*)((char*)Xb + st) = v;
      }
      __syncthreads();
      // ---- logits MFMA: S[r][g] += X[r][d] * W[g][d]
      #pragma unroll
      for (int ks = 0; ks < 4; ++ks) {
        int rowx = Mt * 16 + (lane & 15);
        int bytex = rowx * 256 + (((ks * 64) + ((lane >> 4) * 16)) ^ ((rowx & 7) << 4));
        short8 afr = *(short8*)((char*)Xb + bytex);
        int g = Nt * 16 + (lane & 15);
        int bytew = g * 256 + (((ks * 64) + ((lane >> 4) * 16)) ^ ((g & 7) << 4));
        short8 bfr = *(short8*)((char*)Wb + bytew);
        acc = __builtin_amdgcn_mfma_f32_16x16x32_bf16(afr, bfr, acc, 0, 0, 0);
      }
    }
    // ---- write S tile to LDS (+bias). D-layout: col=lane&15, row=(lane>>4)*4+j
    {
      int g = Nt * 16 + (lane & 15);
      float bs = bias_s[g];
      int rbase = Mt * 16 + (lane >> 4) * 4;
      #pragma unroll
      for (int j = 0; j < 4; ++j) SP[(rbase + j) * 36 + g] = acc[j] + bs;
    }
    __syncthreads();
    // ---- softmax over g (each thread: 1 row, 4 g; 8 threads per row, in-wave)
    {
      int r = t >> 3, gq = t & 7;
      float4 v = *(float4*)(SP + r * 36 + gq * 4);
      float m = fmaxf(fmaxf(v.x, v.y), fmaxf(v.z, v.w));
      m = fmaxf(m, __shfl_xor(m, 1));
      m = fmaxf(m, __shfl_xor(m, 2));
      m = fmaxf(m, __shfl_xor(m, 4));
      v.x = __expf(v.x - m); v.y = __expf(v.y - m);
      v.z = __expf(v.z - m); v.w = __expf(v.w - m);
      float s = v.x + v.y + v.z + v.w;
      s += __shfl_xor(s, 1); s += __shfl_xor(s, 2); s += __shfl_xor(s, 4);
      float inv = 1.0f / s;
      v.x *= inv; v.y *= inv; v.z *= inv; v.w *= inv;
      *(float4*)(SP + r * 36 + gq * 4) = v;
      // column (over-r) partial sums for denom: reduce r-local (lane bits 3..5)
      #pragma unroll
      for (int msk = 8; msk <= 32; msk <<= 1) {
        v.x += __shfl_xor(v.x, msk); v.y += __shfl_xor(v.y, msk);
        v.z += __shfl_xor(v.z, msk); v.w += __shfl_xor(v.w, msk);
      }
      if (lane < 8) {
        atomicAdd(&denom_acc[gq * 4 + 0], v.x);
        atomicAdd(&denom_acc[gq * 4 + 1], v.y);
        atomicAdd(&denom_acc[gq * 4 + 2], v.z);
        atomicAdd(&denom_acc[gq * 4 + 3], v.w);
      }
    }
    __syncthreads();
    // ---- moments: thread owns o-column; part0 -> m1 (mu), part1 -> m2 (mu^2+sg^2)
    {
      int o = t & 255, part = t >> 8;
      const float* xrow = x + ((size_t)b * N_ + r0) * D_;
      #pragma unroll 2
      for (int r = 0; r < 64; ++r) {
        float a0 = xrow[r * D_ + o];
        float val;
        if (part) { float c = xrow[r * D_ + 256 + o]; val = fmaf(a0, a0, c * c); }
        else val = a0;
        const float4* P4 = (const float4*)(SP + r * 36);
        #pragma unroll
        for (int k = 0; k < 8; ++k) {
          float4 p = P4[k];
          macc[k].x = fmaf(p.x, val, macc[k].x);
          macc[k].y = fmaf(p.y, val, macc[k].y);
          macc[k].z = fmaf(p.z, val, macc[k].z);
          macc[k].w = fmaf(p.w, val, macc[k].w);
        }
      }
    }
  }
  __syncthreads();
  // ---- write per-block partials
  {
    int o = t & 255, part = t >> 8;
    float* wsm = ws + (size_t)(bid * 2 + part) * (G_ * O_);
    #pragma unroll
    for (int k = 0; k < 8; ++k) {
      wsm[(k * 4 + 0) * O_ + o] = macc[k].x;
      wsm[(k * 4 + 1) * O_ + o] = macc[k].y;
      wsm[(k * 4 + 2) * O_ + o] = macc[k].z;
      wsm[(k * 4 + 3) * O_ + o] = macc[k].w;
    }
  }
  if (t < G_) ws[4194304 + bid * G_ + t] = denom_acc[t];
}

// Pass 2: reduce 8 chunk-partials per b, finalize weights/scales/locs.
__global__ __launch_bounds__(256) void mdn_pass2(
    const float* __restrict__ ws, float* __restrict__ out)
{
  __shared__ float dnm[G_];
  int b = blockIdx.x, t = threadIdx.x;
  if (t < G_) {
    float s = 0.f;
    #pragma unroll
    for (int c = 0; c < 8; ++c) s += ws[4194304 + (b * 8 + c) * G_ + t];
    dnm[t] = s;
    out[b * G_ + t] = s * (1.0f / 1024.0f);   // weights = denom / N
  }
  __syncthreads();
  float* scales = out + 1024;
  float* locs = out + 1024 + 262144;
  for (int it = 0; it < 32; ++it) {
    int idx = it * 256 + t;
    int g = idx >> 8, o = idx & 255;
    float m1 = 0.f, m2 = 0.f;
    #pragma unroll
    for (int c = 0; c < 8; ++c) {
      size_t base = ((size_t)((b * 8 + c) * 2)) * (G_ * O_) + g * O_ + o;
      m1 += ws[base];
      m2 += ws[base + G_ * O_];
    }
    float dn = dnm[g];
    float lc = m1 / dn;
    float va = m2 / dn - lc * lc;
    int oi = ((b * G_ + g) << 8) + o;
    scales[oi] = sqrtf(fmaxf(va, 0.f));
    locs[oi] = lc;
  }
}

extern "C" void kernel_launch(void* const* d_in, const int* in_sizes, int n_in,
                              void* d_out, int out_size, void* d_ws, size_t ws_size,
                              hipStream_t stream)
{
  const float* x = (const float*)d_in[0];
  const float* W = (const float*)d_in[1];
  const float* bpi = (const float*)d_in[2];
  float* out = (float*)d_out;
  float* ws = (float*)d_ws;
  // ws usage: 256 blocks * 2 parts * 32*256 floats = 16 MiB partials,
  // + 256*32 floats denom partials at offset 4194304. Total ~16.8 MiB.
  hipLaunchKernelGGL(mdn_pass1, dim3(256), dim3(512), 0, stream, x, W, bpi, ws);
  hipLaunchKernelGGL(mdn_pass2, dim3(32), dim3(256), 0, stream, ws, out);
}

// Round 2
// 40.811 us; speedup vs baseline: 1.7593x; 1.7593x over previous
//
#include <hip/hip_runtime.h>
#include <stdint.h>

#define B_ 32
#define N_ 1024
#define D_ 512
#define G_ 32

typedef __attribute__((ext_vector_type(8))) short short8;
typedef __attribute__((ext_vector_type(4))) float f32x4;

union U4S8 { uint4 u; short8 s; };

// round-to-nearest-even fp32 -> bf16 pair packed into u32 (low = a, high = b)
__device__ inline uint32_t pack_bf16x2(float a, float b) {
  uint32_t ua = __float_as_uint(a);
  uint32_t ub = __float_as_uint(b);
  ua += 0x7FFFu + ((ua >> 16) & 1u);
  ub += 0x7FFFu + ((ub >> 16) & 1u);
  return (ua >> 16) | (ub & 0xFFFF0000u);
}

// Pass 1: block = (b, 128-row chunk), 1024 threads (16 waves), 2 blocks/CU.
// Phase A: logits via bf16 MFMA (X,W staged swizzled in LDS).
// Phase B: softmax (fp32), writes pi transposed SPT[g][r] + wave-partial denoms.
// Phase C: moments via bf16 MFMA over 4 o-panels; u staged transposed as
//          bf16 r-pairs XT32[r2][o] (stride 132 u32 -> 16B aligned writes).
__global__ __launch_bounds__(1024, 8) void mdn_pass1(
    const float* __restrict__ x, const float* __restrict__ W,
    const float* __restrict__ bpi, float* __restrict__ ws)
{
  __shared__ uint32_t XU[64 * 132];   // 33792B: logits Xb[128][64u32]; panels XT32[64][132]
  __shared__ uint32_t Wb[32 * 64];    // 8KB swizzled W bf16
  __shared__ float SP[128 * 36];      // logits rows (for softmax)
  __shared__ float SPT[32 * 132];     // pi transposed [g][r], fp32
  __shared__ float wpart[16 * 32];    // per-wave denom partials
  __shared__ float bias_s[G_];

  const int t = threadIdx.x;
  const int bid = blockIdx.x;
  const int b = bid >> 3;
  const int n0 = (bid & 7) * 128;
  const int wave = t >> 6;
  const int lane = t & 63;

  if (t < G_) bias_s[t] = bpi[t];

  // ---------------- Phase A: logits ----------------
  const int Mt = wave >> 1;   // 0..7 : 16-row tile
  const int Nt = wave & 1;    // 0..1 : 16-g tile
  f32x4 acc = {0.f, 0.f, 0.f, 0.f};

  for (int dc = 0; dc < 4; ++dc) {
    __syncthreads();
    if (t < 512) {            // stage W d-chunk (swizzled)
      int st = t * 16;
      int g = st >> 8;
      int d2 = (st & 255) ^ ((g & 7) << 4);
      int d = d2 >> 1;
      const float4* src = (const float4*)(W + g * D_ + dc * 128 + d);
      float4 f0 = src[0], f1 = src[1];
      uint4 v;
      v.x = pack_bf16x2(f0.x, f0.y); v.y = pack_bf16x2(f0.z, f0.w);
      v.z = pack_bf16x2(f1.x, f1.y); v.w = pack_bf16x2(f1.z, f1.w);
      *(uint4*)((char*)Wb + st) = v;
    }
    #pragma unroll
    for (int p = 0; p < 2; ++p) { // stage X d-chunk: 2048 16B slots
      int st = (p * 1024 + t) * 16;
      int r = st >> 8;            // 0..127
      int d2 = (st & 255) ^ ((r & 7) << 4);
      int d = d2 >> 1;
      const float4* src =
          (const float4*)(x + ((size_t)b * N_ + n0 + r) * D_ + dc * 128 + d);
      float4 f0 = src[0], f1 = src[1];
      uint4 v;
      v.x = pack_bf16x2(f0.x, f0.y); v.y = pack_bf16x2(f0.z, f0.w);
      v.z = pack_bf16x2(f1.x, f1.y); v.w = pack_bf16x2(f1.z, f1.w);
      *(uint4*)((char*)XU + st) = v;
    }
    __syncthreads();
    #pragma unroll
    for (int ks = 0; ks < 4; ++ks) {
      int rowx = Mt * 16 + (lane & 15);
      int bytex = rowx * 256 + (((ks * 64) + ((lane >> 4) * 16)) ^ ((rowx & 7) << 4));
      short8 afr = *(short8*)((char*)XU + bytex);
      int g = Nt * 16 + (lane & 15);
      int bytew = g * 256 + (((ks * 64) + ((lane >> 4) * 16)) ^ ((g & 7) << 4));
      short8 bfr = *(short8*)((char*)Wb + bytew);
      acc = __builtin_amdgcn_mfma_f32_16x16x32_bf16(afr, bfr, acc, 0, 0, 0);
    }
  }
  // write logits tile (+bias): D layout col=lane&15 (g), row=(lane>>4)*4+j
  {
    int g = Nt * 16 + (lane & 15);
    float bs = bias_s[g];
    int rbase = Mt * 16 + (lane >> 4) * 4;
    #pragma unroll
    for (int j = 0; j < 4; ++j) SP[(rbase + j) * 36 + g] = acc[j] + bs;
  }
  __syncthreads();

  // ---------------- Phase B: softmax ----------------
  {
    int r = t >> 3, gq = t & 7;   // r 0..127, 8 threads/row
    float4 v = *(float4*)(SP + r * 36 + gq * 4);
    float m = fmaxf(fmaxf(v.x, v.y), fmaxf(v.z, v.w));
    m = fmaxf(m, __shfl_xor(m, 1));
    m = fmaxf(m, __shfl_xor(m, 2));
    m = fmaxf(m, __shfl_xor(m, 4));
    v.x = __expf(v.x - m); v.y = __expf(v.y - m);
    v.z = __expf(v.z - m); v.w = __expf(v.w - m);
    float s = v.x + v.y + v.z + v.w;
    s += __shfl_xor(s, 1); s += __shfl_xor(s, 2); s += __shfl_xor(s, 4);
    float inv = 1.0f / s;
    v.x *= inv; v.y *= inv; v.z *= inv; v.w *= inv;
    // transposed pi store
    SPT[(gq * 4 + 0) * 132 + r] = v.x;
    SPT[(gq * 4 + 1) * 132 + r] = v.y;
    SPT[(gq * 4 + 2) * 132 + r] = v.z;
    SPT[(gq * 4 + 3) * 132 + r] = v.w;
    // per-wave column sums (8 rows per wave, lane bits 3..5)
    #pragma unroll
    for (int msk = 8; msk <= 32; msk <<= 1) {
      v.x += __shfl_xor(v.x, msk); v.y += __shfl_xor(v.y, msk);
      v.z += __shfl_xor(v.z, msk); v.w += __shfl_xor(v.w, msk);
    }
    if (lane < 8) {
      wpart[wave * 32 + lane * 4 + 0] = v.x;
      wpart[wave * 32 + lane * 4 + 1] = v.y;
      wpart[wave * 32 + lane * 4 + 2] = v.z;
      wpart[wave * 32 + lane * 4 + 3] = v.w;
    }
  }
  __syncthreads();
  // deterministic denom partial write (fixed order)
  if (t < G_) {
    float s = 0.f;
    #pragma unroll
    for (int w = 0; w < 16; ++w) s += wpart[w * 32 + t];
    ws[4194304 + bid * G_ + t] = s;
  }

  // ---------------- Phase C: moments ----------------
  const int gt = wave >> 3;       // 0..1 : 16-g tile
  const int ot = wave & 7;        // 0..7 : 16-o tile (panel-local)
  // hoist A-frags (pi^T, bf16) into registers: 4 k-steps
  short8 paf[4];
  {
    int ga = gt * 16 + (lane & 15);
    #pragma unroll
    for (int ks = 0; ks < 4; ++ks) {
      int r0 = ks * 32 + (lane >> 4) * 8;
      float4 fa = *(float4*)(SPT + ga * 132 + r0);
      float4 fb = *(float4*)(SPT + ga * 132 + r0 + 4);
      U4S8 c;
      c.u.x = pack_bf16x2(fa.x, fa.y); c.u.y = pack_bf16x2(fa.z, fa.w);
      c.u.z = pack_bf16x2(fb.x, fb.y); c.u.w = pack_bf16x2(fb.z, fb.w);
      paf[ks] = c.s;
    }
  }

  uint32_t* XT = XU;              // reuse as XT32[64 r2][132]
  for (int p = 0; p < 4; ++p) {
    __syncthreads();
    // stage u^T panel p: u col range [p*128,(p+1)*128) of [mu | mu^2+sigma^2]
    #pragma unroll
    for (int i = 0; i < 2; ++i) {
      int slot = i * 1024 + t;
      int o4 = slot & 31;         // o = 4*o4 panel-local
      int r2 = slot >> 5;         // 0..63, rows 2*r2, 2*r2+1
      const float* base = x + ((size_t)b * N_ + n0 + 2 * r2) * D_;
      float4 v0, v1;
      if (p < 2) {
        v0 = *(const float4*)(base + p * 128 + 4 * o4);
        v1 = *(const float4*)(base + D_ + p * 128 + 4 * o4);
      } else {
        float4 a0 = *(const float4*)(base + (p - 2) * 128 + 4 * o4);
        float4 b0 = *(const float4*)(base + 256 + (p - 2) * 128 + 4 * o4);
        float4 a1 = *(const float4*)(base + D_ + (p - 2) * 128 + 4 * o4);
        float4 b1 = *(const float4*)(base + D_ + 256 + (p - 2) * 128 + 4 * o4);
        v0 = make_float4(fmaf(a0.x, a0.x, b0.x * b0.x), fmaf(a0.y, a0.y, b0.y * b0.y),
                         fmaf(a0.z, a0.z, b0.z * b0.z), fmaf(a0.w, a0.w, b0.w * b0.w));
        v1 = make_float4(fmaf(a1.x, a1.x, b1.x * b1.x), fmaf(a1.y, a1.y, b1.y * b1.y),
                         fmaf(a1.z, a1.z, b1.z * b1.z), fmaf(a1.w, a1.w, b1.w * b1.w));
      }
      uint4 w;
      w.x = pack_bf16x2(v0.x, v1.x); w.y = pack_bf16x2(v0.y, v1.y);
      w.z = pack_bf16x2(v0.z, v1.z); w.w = pack_bf16x2(v0.w, v1.w);
      *(uint4*)(XT + r2 * 132 + 4 * o4) = w;   // 16B aligned (132*4 % 16 == 0)
    }
    __syncthreads();
    // MFMA: wave computes its 16x16 (g,o) tile for this panel
    f32x4 acc2 = {0.f, 0.f, 0.f, 0.f};
    int ol = ot * 16 + (lane & 15);
    #pragma unroll
    for (int ks = 0; ks < 4; ++ks) {
      int rb = ks * 16 + (lane >> 4) * 4;
      U4S8 c;
      c.u.x = XT[(rb + 0) * 132 + ol];
      c.u.y = XT[(rb + 1) * 132 + ol];
      c.u.z = XT[(rb + 2) * 132 + ol];
      c.u.w = XT[(rb + 3) * 132 + ol];
      acc2 = __builtin_amdgcn_mfma_f32_16x16x32_bf16(paf[ks], c.s, acc2, 0, 0, 0);
    }
    // store partial tile: ws[bid][g][o], o in [0,512) = [m1 | m2]
    float* dst = ws + (size_t)bid * 16384;
    int gout = gt * 16 + (lane >> 4) * 4;
    int col = p * 128 + ol;
    #pragma unroll
    for (int j = 0; j < 4; ++j) dst[(gout + j) * 512 + col] = acc2[j];
  }
}

// Pass 2: block = (b, 32-wide o chunk); reduce 8 row-chunk partials, finalize.
__global__ __launch_bounds__(256) void mdn_pass2(
    const float* __restrict__ ws, float* __restrict__ out)
{
  __shared__ float dnm[G_];
  int blk = blockIdx.x;
  int b = blk >> 3, oc = blk & 7;
  int t = threadIdx.x;
  if (t < G_) {
    float s = 0.f;
    #pragma unroll
    for (int c = 0; c < 8; ++c) s += ws[4194304 + (b * 8 + c) * G_ + t];
    dnm[t] = s;
    if (oc == 0) out[b * G_ + t] = s * (1.0f / 1024.0f);  // weights
  }
  __syncthreads();
  int g = t >> 3;
  int o = oc * 32 + (t & 7) * 4;
  float4 m1 = make_float4(0.f, 0.f, 0.f, 0.f);
  float4 m2 = make_float4(0.f, 0.f, 0.f, 0.f);
  #pragma unroll
  for (int c = 0; c < 8; ++c) {
    const float* p = ws + (size_t)(b * 8 + c) * 16384 + g * 512;
    float4 a = *(const float4*)(p + o);
    float4 bb = *(const float4*)(p + 256 + o);
    m1.x += a.x; m1.y += a.y; m1.z += a.z; m1.w += a.w;
    m2.x += bb.x; m2.y += bb.y; m2.z += bb.z; m2.w += bb.w;
  }
  float dn = dnm[g];
  float inv = 1.0f / dn;
  float4 lc = make_float4(m1.x * inv, m1.y * inv, m1.z * inv, m1.w * inv);
  float4 sc;
  sc.x = sqrtf(fmaxf(m2.x * inv - lc.x * lc.x, 0.f));
  sc.y = sqrtf(fmaxf(m2.y * inv - lc.y * lc.y, 0.f));
  sc.z = sqrtf(fmaxf(m2.z * inv - lc.z * lc.z, 0.f));
  sc.w = sqrtf(fmaxf(m2.w * inv - lc.w * lc.w, 0.f));
  float* scales = out + 1024;
  float* locs = out + 1024 + 262144;
  int oi = ((b * G_ + g) << 8) + o;
  *(float4*)(scales + oi) = sc;
  *(float4*)(locs + oi) = lc;
}

extern "C" void kernel_launch(void* const* d_in, const int* in_sizes, int n_in,
                              void* d_out, int out_size, void* d_ws, size_t ws_size,
                              hipStream_t stream)
{
  const float* x = (const float*)d_in[0];
  const float* W = (const float*)d_in[1];
  const float* bpi = (const float*)d_in[2];
  float* out = (float*)d_out;
  float* ws = (float*)d_ws;
  // ws: 256 blocks * 32g * 512o floats = 16 MiB partials at 0,
  //     + 256*32 denom partials at float offset 4194304. Total 16.81 MiB.
  hipLaunchKernelGGL(mdn_pass1, dim3(256), dim3(1024), 0, stream, x, W, bpi, ws);
  hipLaunchKernelGGL(mdn_pass2, dim3(256), dim3(256), 0, stream, ws, out);
}

// Round 3
// 35.402 us; speedup vs baseline: 2.0281x; 1.1528x over previous
//
#include <hip/hip_runtime.h>
#include <stdint.h>

#define B_ 32
#define N_ 1024
#define D_ 512
#define G_ 32

typedef __attribute__((ext_vector_type(8))) short short8;
typedef __attribute__((ext_vector_type(4))) float f32x4;

union U4S8 { uint4 u; short8 s; };

// ws float-offsets:
//   WS_PIT: piT bf16 [32 b][32 g][1024 n]  = 2 MB
//   WS_M  : K2 partials, 512 blocks x [32 g][128] = 8 MB
//   WS_DN : K1 denom partials, 512 x 32 = 64 KB
#define WS_M   524288
#define WS_DN  2621440

__device__ inline uint32_t pack_bf16x2(float a, float b) {
  uint32_t ua = __float_as_uint(a);
  uint32_t ub = __float_as_uint(b);
  ua += 0x7FFFu + ((ua >> 16) & 1u);
  ub += 0x7FFFu + ((ub >> 16) & 1u);
  return (ua >> 16) | (ub & 0xFFFF0000u);
}
__device__ inline uint16_t bf16r(float a) {
  uint32_t u = __float_as_uint(a);
  u += 0x7FFFu + ((u >> 16) & 1u);
  return (uint16_t)(u >> 16);
}

// ---------------- K1: logits MFMA + softmax -> piT(bf16) + denom partials ----
// block = (b, 64-row chunk); 512 threads (8 waves); reg-prefetch pipelined.
__global__ __launch_bounds__(512, 8) void mdn_k1(
    const float* __restrict__ x, const float* __restrict__ W,
    const float* __restrict__ bpi, float* ws)
{
  __shared__ uint32_t Xb[4096];     // 16KB: 64r x 128d bf16, swizzled
  __shared__ uint32_t Wb[2048];     // 8KB : 32g x 128d bf16, swizzled
  __shared__ float SP[64 * 36];     // logits
  __shared__ uint32_t SPTb[1024];   // 4KB : pi^T bf16 [32 g][32 u32 = 64 r]
  __shared__ float wpart[8 * 32];
  __shared__ float bias_s[G_];

  const int t = threadIdx.x;
  const int bid = blockIdx.x;
  const int b = bid >> 4;
  const int n0 = (bid & 15) * 64;
  const int wave = t >> 6;
  const int lane = t & 63;
  const int Mt = wave >> 1;   // row tile 0..3
  const int Nt = wave & 1;    // g tile 0..1

  // staging address decode (constant over dc)
  int xr[2], xd[2];
  #pragma unroll
  for (int p = 0; p < 2; ++p) {
    int st = (p * 512 + t) * 16;
    xr[p] = st >> 8;
    xd[p] = ((st & 255) ^ ((xr[p] & 7) << 4)) >> 1;
  }
  int wg, wd;
  { int st = t * 16; wg = st >> 8; wd = ((st & 255) ^ ((wg & 7) << 4)) >> 1; }

  const float* xbase = x + ((size_t)b * N_ + n0) * D_;

  // prologue: dc=0 loads into regs
  float4 fx[2][2], fw[2];
  #pragma unroll
  for (int p = 0; p < 2; ++p) {
    const float* s = xbase + xr[p] * D_ + xd[p];
    fx[p][0] = *(const float4*)s; fx[p][1] = *(const float4*)(s + 4);
  }
  { const float* s = W + wg * D_ + wd;
    fw[0] = *(const float4*)s; fw[1] = *(const float4*)(s + 4); }

  if (t < G_) bias_s[t] = bpi[t];

  f32x4 acc = {0.f, 0.f, 0.f, 0.f};

  #pragma unroll
  for (int dc = 0; dc < 4; ++dc) {
    // write staged regs -> LDS (bf16 packed)
    #pragma unroll
    for (int p = 0; p < 2; ++p) {
      uint4 v;
      v.x = pack_bf16x2(fx[p][0].x, fx[p][0].y); v.y = pack_bf16x2(fx[p][0].z, fx[p][0].w);
      v.z = pack_bf16x2(fx[p][1].x, fx[p][1].y); v.w = pack_bf16x2(fx[p][1].z, fx[p][1].w);
      *(uint4*)((char*)Xb + (p * 512 + t) * 16) = v;
    }
    {
      uint4 v;
      v.x = pack_bf16x2(fw[0].x, fw[0].y); v.y = pack_bf16x2(fw[0].z, fw[0].w);
      v.z = pack_bf16x2(fw[1].x, fw[1].y); v.w = pack_bf16x2(fw[1].z, fw[1].w);
      *(uint4*)((char*)Wb + t * 16) = v;
    }
    __syncthreads();
    if (dc < 3) {  // issue next-chunk loads; they overlap the MFMAs below
      #pragma unroll
      for (int p = 0; p < 2; ++p) {
        const float* s = xbase + xr[p] * D_ + (dc + 1) * 128 + xd[p];
        fx[p][0] = *(const float4*)s; fx[p][1] = *(const float4*)(s + 4);
      }
      const float* s = W + wg * D_ + (dc + 1) * 128 + wd;
      fw[0] = *(const float4*)s; fw[1] = *(const float4*)(s + 4);
    }
    #pragma unroll
    for (int ks = 0; ks < 4; ++ks) {
      int rowx = Mt * 16 + (lane & 15);
      int bytex = rowx * 256 + (((ks * 64) + ((lane >> 4) * 16)) ^ ((rowx & 7) << 4));
      short8 afr = *(short8*)((char*)Xb + bytex);
      int g = Nt * 16 + (lane & 15);
      int bytew = g * 256 + (((ks * 64) + ((lane >> 4) * 16)) ^ ((g & 7) << 4));
      short8 bfr = *(short8*)((char*)Wb + bytew);
      acc = __builtin_amdgcn_mfma_f32_16x16x32_bf16(afr, bfr, acc, 0, 0, 0);
    }
    __syncthreads();
  }

  // logits tile -> SP (+bias). C layout: col=lane&15 (g), row=(lane>>4)*4+j
  {
    int g = Nt * 16 + (lane & 15);
    float bs = bias_s[g];
    int rbase = Mt * 16 + (lane >> 4) * 4;
    #pragma unroll
    for (int j = 0; j < 4; ++j) SP[(rbase + j) * 36 + g] = acc[j] + bs;
  }
  __syncthreads();

  // softmax: thread = (row r = t>>3, g-quad gq = t&7)
  {
    int r = t >> 3, gq = t & 7;
    float4 v = *(float4*)(SP + r * 36 + gq * 4);
    float m = fmaxf(fmaxf(v.x, v.y), fmaxf(v.z, v.w));
    m = fmaxf(m, __shfl_xor(m, 1));
    m = fmaxf(m, __shfl_xor(m, 2));
    m = fmaxf(m, __shfl_xor(m, 4));
    v.x = __expf(v.x - m); v.y = __expf(v.y - m);
    v.z = __expf(v.z - m); v.w = __expf(v.w - m);
    float s = v.x + v.y + v.z + v.w;
    s += __shfl_xor(s, 1); s += __shfl_xor(s, 2); s += __shfl_xor(s, 4);
    float inv = 1.0f / s;
    v.x *= inv; v.y *= inv; v.z *= inv; v.w *= inv;
    uint16_t* sp16 = (uint16_t*)SPTb;
    sp16[(gq * 4 + 0) * 64 + r] = bf16r(v.x);
    sp16[(gq * 4 + 1) * 64 + r] = bf16r(v.y);
    sp16[(gq * 4 + 2) * 64 + r] = bf16r(v.z);
    sp16[(gq * 4 + 3) * 64 + r] = bf16r(v.w);
    // per-wave column sums over the wave's 8 rows (lane bits 3..5)
    #pragma unroll
    for (int msk = 8; msk <= 32; msk <<= 1) {
      v.x += __shfl_xor(v.x, msk); v.y += __shfl_xor(v.y, msk);
      v.z += __shfl_xor(v.z, msk); v.w += __shfl_xor(v.w, msk);
    }
    if (lane < 8) {
      wpart[wave * 32 + lane * 4 + 0] = v.x;
      wpart[wave * 32 + lane * 4 + 1] = v.y;
      wpart[wave * 32 + lane * 4 + 2] = v.z;
      wpart[wave * 32 + lane * 4 + 3] = v.w;
    }
  }
  __syncthreads();

  // piT global write: [b][g][n] bf16, this block's 64-n slice
  if (t < 256) {
    int g = t >> 3, s = t & 7;
    uint4 v = *(uint4*)(SPTb + g * 32 + s * 4);
    *(uint4*)((uint32_t*)ws + (size_t)(b * 32 + g) * 512 + (n0 >> 1) + s * 4) = v;
  }
  if (t < G_) {
    float ssum = 0.f;
    #pragma unroll
    for (int w = 0; w < 8; ++w) ssum += wpart[w * 32 + t];
    ws[WS_DN + bid * 32 + t] = ssum;
  }
}

// ---------------- K2: moments GEMM m = piT (bf16) x u, K-chunked ------------
// block = (b, kc 256-row chunk, q 64-o slice). Computes [32 g][64 m1 | 64 m2].
__global__ __launch_bounds__(512, 8) void mdn_k2(
    const float* __restrict__ x, float* ws)
{
  __shared__ uint32_t PT[32 * 132];  // piT chunk [g][128 u32 = 256 r], stride 132
  __shared__ uint32_t XT[32 * 132];  // u^T sub-chunk [r2][128 cols], stride 132

  const int t = threadIdx.x;
  const int bid = blockIdx.x;
  const int b = bid >> 4;
  const int kc = (bid >> 2) & 3;
  const int q = bid & 3;
  const int wave = t >> 6, lane = t & 63;
  const int ot = wave;               // o-tile 0..7 (cols 0..127 = m1|m2)
  const int n0 = kc * 256;

  // prologue: piT loads (2x uint4) + x sub-chunk 0 loads
  const uint32_t* piT = (const uint32_t*)ws;
  const int pg = t >> 4, psl = t & 15;
  const uint32_t* pbase = piT + (size_t)(b * 32 + pg) * 512 + kc * 128;
  uint4 pv0 = *(const uint4*)(pbase + psl * 4);
  uint4 pv1 = *(const uint4*)(pbase + (psl + 16) * 4);

  const int r2l = t >> 4, c4 = t & 15;
  const float* xb2 = x + ((size_t)b * N_ + n0) * D_ + q * 64 + 4 * c4;
  float4 a0, a1, sv0, sv1;
  {
    const float* s = xb2 + (size_t)(2 * r2l) * D_;
    a0 = *(const float4*)s;        a1 = *(const float4*)(s + D_);
    sv0 = *(const float4*)(s + 256); sv1 = *(const float4*)(s + D_ + 256);
  }

  *(uint4*)(PT + pg * 132 + psl * 4) = pv0;
  *(uint4*)(PT + pg * 132 + (psl + 16) * 4) = pv1;
  __syncthreads();

  f32x4 acc[2] = {{0.f,0.f,0.f,0.f},{0.f,0.f,0.f,0.f}};

  #pragma unroll
  for (int sc = 0; sc < 4; ++sc) {
    // pack staged regs -> XT: mu pairs at cols [0,64), mu^2+sg^2 at [64,128)
    {
      uint4 wmu, wm2;
      wmu.x = pack_bf16x2(a0.x, a1.x); wmu.y = pack_bf16x2(a0.y, a1.y);
      wmu.z = pack_bf16x2(a0.z, a1.z); wmu.w = pack_bf16x2(a0.w, a1.w);
      float4 u0 = make_float4(fmaf(a0.x, a0.x, sv0.x * sv0.x), fmaf(a0.y, a0.y, sv0.y * sv0.y),
                              fmaf(a0.z, a0.z, sv0.z * sv0.z), fmaf(a0.w, a0.w, sv0.w * sv0.w));
      float4 u1 = make_float4(fmaf(a1.x, a1.x, sv1.x * sv1.x), fmaf(a1.y, a1.y, sv1.y * sv1.y),
                              fmaf(a1.z, a1.z, sv1.z * sv1.z), fmaf(a1.w, a1.w, sv1.w * sv1.w));
      wm2.x = pack_bf16x2(u0.x, u1.x); wm2.y = pack_bf16x2(u0.y, u1.y);
      wm2.z = pack_bf16x2(u0.z, u1.z); wm2.w = pack_bf16x2(u0.w, u1.w);
      *(uint4*)(XT + r2l * 132 + 4 * c4) = wmu;
      *(uint4*)(XT + r2l * 132 + 64 + 4 * c4) = wm2;
    }
    __syncthreads();
    if (sc < 3) {  // prefetch next 64-row sub-chunk
      const float* s = xb2 + (size_t)((sc + 1) * 64 + 2 * r2l) * D_;
      a0 = *(const float4*)s;        a1 = *(const float4*)(s + D_);
      sv0 = *(const float4*)(s + 256); sv1 = *(const float4*)(s + D_ + 256);
    }
    #pragma unroll
    for (int kl = 0; kl < 2; ++kl) {
      int rb = kl * 16 + (lane >> 4) * 4;
      int ol = ot * 16 + (lane & 15);
      U4S8 bf;
      bf.u.x = XT[(rb + 0) * 132 + ol];
      bf.u.y = XT[(rb + 1) * 132 + ol];
      bf.u.z = XT[(rb + 2) * 132 + ol];
      bf.u.w = XT[(rb + 3) * 132 + ol];
      int r0h = (sc * 2 + kl) * 16 + (lane >> 4) * 4;   // u32 offset of 8-r run
      #pragma unroll
      for (int gt = 0; gt < 2; ++gt) {
        int ga = gt * 16 + (lane & 15);
        short8 af = *(short8*)((char*)PT + (ga * 132 + r0h) * 4);
        acc[gt] = __builtin_amdgcn_mfma_f32_16x16x32_bf16(af, bf.s, acc[gt], 0, 0, 0);
      }
    }
    __syncthreads();
  }

  // write partial [32 g][128]
  float* dst = ws + WS_M + (size_t)bid * 4096;
  #pragma unroll
  for (int gt = 0; gt < 2; ++gt) {
    int gout = gt * 16 + (lane >> 4) * 4;
    int col = ot * 16 + (lane & 15);
    #pragma unroll
    for (int j = 0; j < 4; ++j) dst[(gout + j) * 128 + col] = acc[gt][j];
  }
}

// ---------------- K3: reduce partials + finalize ----------------------------
__global__ __launch_bounds__(256) void mdn_k3(
    const float* __restrict__ ws, float* __restrict__ out)
{
  __shared__ float dnm[G_];
  const int blk = blockIdx.x;
  const int b = blk >> 3, oc = blk & 7;   // oc: 32-wide o chunk
  const int t = threadIdx.x;
  if (t < G_) {
    float s = 0.f;
    #pragma unroll
    for (int c = 0; c < 16; ++c) s += ws[WS_DN + (b * 16 + c) * 32 + t];
    dnm[t] = s;
    if (oc == 0) out[b * G_ + t] = s * (1.0f / 1024.0f);   // weights
  }
  __syncthreads();
  const int g = t >> 3;
  const int o = oc * 32 + (t & 7) * 4;
  const int q = o >> 6;         // uniform per block
  const int col = o & 63;
  float4 m1 = make_float4(0.f, 0.f, 0.f, 0.f);
  float4 m2 = make_float4(0.f, 0.f, 0.f, 0.f);
  #pragma unroll
  for (int kc = 0; kc < 4; ++kc) {
    const float* p = ws + WS_M + (size_t)((b * 16 + kc * 4 + q)) * 4096 + g * 128;
    float4 a = *(const float4*)(p + col);
    float4 c2 = *(const float4*)(p + 64 + col);
    m1.x += a.x; m1.y += a.y; m1.z += a.z; m1.w += a.w;
    m2.x += c2.x; m2.y += c2.y; m2.z += c2.z; m2.w += c2.w;
  }
  float inv = 1.0f / dnm[g];
  float4 lc = make_float4(m1.x * inv, m1.y * inv, m1.z * inv, m1.w * inv);
  float4 sc;
  sc.x = sqrtf(fmaxf(m2.x * inv - lc.x * lc.x, 0.f));
  sc.y = sqrtf(fmaxf(m2.y * inv - lc.y * lc.y, 0.f));
  sc.z = sqrtf(fmaxf(m2.z * inv - lc.z * lc.z, 0.f));
  sc.w = sqrtf(fmaxf(m2.w * inv - lc.w * lc.w, 0.f));
  float* scales = out + 1024;
  float* locs = out + 1024 + 262144;
  int oi = ((b * G_ + g) << 8) + o;
  *(float4*)(scales + oi) = sc;
  *(float4*)(locs + oi) = lc;
}

extern "C" void kernel_launch(void* const* d_in, const int* in_sizes, int n_in,
                              void* d_out, int out_size, void* d_ws, size_t ws_size,
                              hipStream_t stream)
{
  const float* x = (const float*)d_in[0];
  const float* W = (const float*)d_in[1];
  const float* bpi = (const float*)d_in[2];
  float* out = (float*)d_out;
  float* ws = (float*)d_ws;
  // ws: [0,2MB) piT bf16; [2MB,10MB) K2 partials; then 64KB denom partials.
  hipLaunchKernelGGL(mdn_k1, dim3(512), dim3(512), 0, stream, x, W, bpi, ws);
  hipLaunchKernelGGL(mdn_k2, dim3(512), dim3(512), 0, stream, x, ws);
  hipLaunchKernelGGL(mdn_k3, dim3(256), dim3(256), 0, stream, ws, out);
}